// Round 3
// baseline (143.870 us; speedup 1.0000x reference)
//
#include <hip/hip_runtime.h>
#include <math.h>

#define TB 256
#define PI_F 3.14159265358979323846f

#define WAIT_VM4() asm volatile("s_waitcnt vmcnt(4)" ::: "memory")
#define WAIT_VM0() asm volatile("s_waitcnt vmcnt(0)" ::: "memory")

typedef __attribute__((address_space(1))) const void GlobalVoid;
typedef __attribute__((address_space(3))) void LdsVoid;

__device__ __forceinline__ float fast_tanh(float p) {
    float t = __expf(2.0f * p);
    return 1.0f - __fdividef(2.0f, t + 1.0f);
}

__global__ __launch_bounds__(TB) void sqru_fused_kernel(
    const float* __restrict__ x, const float* __restrict__ Wp,
    const float* __restrict__ bp, const float* __restrict__ qw,
    const float* __restrict__ W1, const float* __restrict__ b1,
    const float* __restrict__ W2, const float* __restrict__ b2,
    float* __restrict__ out, int nrows)
{
    __shared__ float wp_s[16 * 256];   // 16 KB
    __shared__ float xbuf[2 * 4096];   // 32 KB: 2 bufs x [4 waves][64 rows][16 floats]
    __shared__ float w1_s[32 * 8];
    __shared__ float w2_s[10 * 32];
    __shared__ float b1_s[32];
    __shared__ float b2_s[10];
    __shared__ float bp_s[16];
    __shared__ float rot_s[8][3][6];

    const int t = threadIdx.x;

    // ---- stage weights to LDS (coalesced), one-time barrier ----
    ((float4*)wp_s)[t]        = ((const float4*)Wp)[t];
    ((float4*)wp_s)[t + 256]  = ((const float4*)Wp)[t + 256];
    ((float4*)wp_s)[t + 512]  = ((const float4*)Wp)[t + 512];
    ((float4*)wp_s)[t + 768]  = ((const float4*)Wp)[t + 768];
    if (t < 64) ((float4*)w1_s)[t] = ((const float4*)W1)[t];
    if (t < 80) ((float4*)w2_s)[t] = ((const float4*)W2)[t];
    if (t < 32) b1_s[t] = b1[t];
    if (t < 10) b2_s[t] = b2[t];
    if (t < 16) bp_s[t] = bp[t];
    if (t < 24) {
        int u = t / 3, l = t % 3;
        float q0 = qw[u * 9 + l * 3 + 0];
        float q1 = qw[u * 9 + l * 3 + 1];
        float q2 = qw[u * 9 + l * 3 + 2];
        rot_s[u][l][0] = cosf(q0);        rot_s[u][l][1] = sinf(q0);
        rot_s[u][l][2] = cosf(0.5f * q1); rot_s[u][l][3] = sinf(0.5f * q1);
        rot_s[u][l][4] = cosf(q2);        rot_s[u][l][5] = sinf(q2);
    }
    __syncthreads();   // also drains all prior vmem: vmcnt==0 here

    const int w  = t >> 6;            // wave id
    const int k  = t & 63;            // lane
    const int row0w = blockIdx.x * TB + w * 64;
    const int row   = blockIdx.x * TB + t;   // == row0w + k

    // stage-side lane mapping: lane k covers local row lrs=k>>2, slot k&3.
    // slot s of row r holds global col-part s ^ g(r), g(r)=(r&3)^((r>>2)&3):
    // makes consumer ds_read_b128 hit all 8 bank-quads (conflict-free minimum).
    const int lrs = k >> 2;
    const int pss = (k & 3) ^ ((lrs & 3) ^ ((lrs >> 2) & 3));
    // consumer-side: my row's XOR key
    const int gc  = (k & 3) ^ ((k >> 2) & 3);

    float acc[16];

    auto stage = [&](int bb, int cc) {   // wave stages its own 64 rows x 16 cols
        #pragma unroll
        for (int i = 0; i < 4; ++i) {
            int r = row0w + i * 16 + lrs;
            r = (r < nrows) ? r : (nrows - 1);
            const float* src = x + (size_t)r * 256 + (cc << 4) + (pss << 2);
            float* dstf = &xbuf[(bb << 12) + (w << 10) + (i << 8)];  // wave-uniform
            __builtin_amdgcn_global_load_lds((GlobalVoid*)src, (LdsVoid*)dstf, 16, 0, 0);
        }
    };

    auto compute_chunk = [&](int bb, int cc) {
        const float* xb = &xbuf[(bb << 12) + (w << 10) + (k << 4)];
        #pragma unroll
        for (int p = 0; p < 4; ++p) {
            float4 xv = *(const float4*)(xb + ((p ^ gc) << 2));
            const float* wpc = &wp_s[(cc << 4) + (p << 2)];
            #pragma unroll
            for (int j = 0; j < 16; ++j) {
                float4 wv = *(const float4*)(wpc + (j << 8));  // broadcast
                acc[j] = fmaf(xv.x, wv.x, acc[j]);
                acc[j] = fmaf(xv.y, wv.y, acc[j]);
                acc[j] = fmaf(xv.z, wv.z, acc[j]);
                acc[j] = fmaf(xv.w, wv.w, acc[j]);
            }
        }
    };

    // ---- DMA-pipelined GEMV: 16 chunks of 16 cols, 2 buffers, 2 ahead ----
    stage(0, 0);
    stage(1, 1);
    #pragma unroll
    for (int j = 0; j < 16; ++j) acc[j] = bp_s[j];

    for (int cc2 = 0; cc2 < 8; ++cc2) {
        const int c0 = cc2 * 2;
        WAIT_VM4();                       // chunk c0 landed (c0+1 still in flight)
        compute_chunk(0, c0);
        if (cc2 < 7) stage(0, c0 + 2);
        if (cc2 < 7) { WAIT_VM4(); } else { WAIT_VM0(); }
        compute_chunk(1, c0 + 1);
        if (cc2 < 7) stage(1, c0 + 3);
    }

    // ---- 8 single-qubit circuits (per-thread, no redundancy) ----
    float q[8];
    #pragma unroll
    for (int u = 0; u < 8; ++u) {
        float th0 = fast_tanh(acc[2 * u + 0]);
        float th1 = fast_tanh(acc[2 * u + 1]);
        float c  = __cosf(0.5f * PI_F * th0);
        float s  = __sinf(0.5f * PI_F * th0);
        float zr = __cosf(PI_F * th1);
        float zi = __sinf(PI_F * th1);

        float ar = c, ai = 0.0f, br = s, bi = 0.0f;  // layer-0 RY on |0>
        #pragma unroll
        for (int l = 0; l < 3; ++l) {
            if (l > 0) {
                float nar = c * ar - s * br, nai = c * ai - s * bi;
                float nbr = s * ar + c * br, nbi = s * ai + c * bi;
                ar = nar; ai = nai; br = nbr; bi = nbi;
            }
            float e0r = rot_s[u][l][0], e0i = rot_s[u][l][1];
            float pr = zr * e0r - zi * e0i;
            float pq = zr * e0i + zi * e0r;
            float nbr = br * pr - bi * pq, nbi = br * pq + bi * pr;
            br = nbr; bi = nbi;
            float c1 = rot_s[u][l][2], s1 = rot_s[u][l][3];
            float tar = c1 * ar - s1 * br, tai = c1 * ai - s1 * bi;
            float tbr = s1 * ar + c1 * br, tbi = s1 * ai + c1 * bi;
            ar = tar; ai = tai; br = tbr; bi = tbi;
            if (l < 2) {
                float e2r = rot_s[u][l][4], e2i = rot_s[u][l][5];
                float ubr = br * e2r - bi * e2i, ubi = br * e2i + bi * e2r;
                br = ubr; bi = ubi;
            }
        }
        q[u] = (ar * ar + ai * ai) - (br * br + bi * bi);
    }

    // ---- head: relu(q @ W1^T + b1) @ W2^T + b2 ----
    float ov[10];
    #pragma unroll
    for (int c2 = 0; c2 < 10; ++c2) ov[c2] = b2_s[c2];
    #pragma unroll
    for (int j = 0; j < 32; ++j) {
        float h = b1_s[j];
        #pragma unroll
        for (int u = 0; u < 8; ++u) h = fmaf(q[u], w1_s[j * 8 + u], h);
        h = fmaxf(h, 0.0f);
        #pragma unroll
        for (int c2 = 0; c2 < 10; ++c2) ov[c2] = fmaf(h, w2_s[c2 * 32 + j], ov[c2]);
    }

    // ---- write 40B/row as 5x float2 ----
    if (row < nrows) {
        float2* orow = (float2*)(out + (size_t)row * 10);
        orow[0] = make_float2(ov[0], ov[1]);
        orow[1] = make_float2(ov[2], ov[3]);
        orow[2] = make_float2(ov[4], ov[5]);
        orow[3] = make_float2(ov[6], ov[7]);
        orow[4] = make_float2(ov[8], ov[9]);
    }
}

extern "C" void kernel_launch(void* const* d_in, const int* in_sizes, int n_in,
                              void* d_out, int out_size, void* d_ws, size_t ws_size,
                              hipStream_t stream) {
    const float* x  = (const float*)d_in[0];
    const float* Wp = (const float*)d_in[1];
    const float* bp = (const float*)d_in[2];
    const float* qw = (const float*)d_in[3];
    const float* W1 = (const float*)d_in[4];
    const float* b1 = (const float*)d_in[5];
    const float* W2 = (const float*)d_in[6];
    const float* b2 = (const float*)d_in[7];
    float* out = (float*)d_out;

    const int nrows = in_sizes[0] / 256;
    const int nblocks = (nrows + TB - 1) / TB;
    sqru_fused_kernel<<<nblocks, TB, 0, stream>>>(x, Wp, bp, qw, W1, b1, W2, b2, out, nrows);
}

// Round 4
// 37.787 us; speedup vs baseline: 3.8074x; 3.8074x over previous
//
#include <hip/hip_runtime.h>
#include <math.h>

#define TB 256
#define PI_F 3.14159265358979323846f

typedef __attribute__((ext_vector_type(8))) short short8;
typedef __attribute__((ext_vector_type(4))) float f32x4;

union Frag { short8 v; ushort u[8]; };

// round-to-nearest-even fp32 -> bf16 bits
__device__ __forceinline__ uint f2bf_bits(float f) {
    uint b = __float_as_uint(f);
    return (b + 0x7fffu + ((b >> 16) & 1u)) >> 16;
}
__device__ __forceinline__ float bf2f(uint hb) {
    return __uint_as_float(hb << 16);
}

__device__ __forceinline__ float fast_tanh(float p) {
    float t = __expf(2.0f * p);
    return 1.0f - __fdividef(2.0f, t + 1.0f);
}

__global__ __launch_bounds__(TB) void sqru_fused_kernel(
    const float* __restrict__ x, const float* __restrict__ Wp,
    const float* __restrict__ bp, const float* __restrict__ qw,
    const float* __restrict__ W1, const float* __restrict__ b1,
    const float* __restrict__ W2, const float* __restrict__ b2,
    float* __restrict__ out, int nrows)
{
    __shared__ float proj_s[4][64 * 20];   // per-wave transpose buffer, stride 20 (bank-spread)
    __shared__ float w1_s[32 * 8];
    __shared__ float w2_s[10 * 32];
    __shared__ float b1_s[32];
    __shared__ float b2_s[10];
    __shared__ float rot_s[8][3][6];

    const int t = threadIdx.x;

    if (t < 64) ((float4*)w1_s)[t] = ((const float4*)W1)[t];
    if (t < 80) ((float4*)w2_s)[t] = ((const float4*)W2)[t];
    if (t < 32) b1_s[t] = b1[t];
    if (t < 10) b2_s[t] = b2[t];
    if (t < 24) {
        int u = t / 3, l2 = t % 3;
        float q0 = qw[u * 9 + l2 * 3 + 0];
        float q1 = qw[u * 9 + l2 * 3 + 1];
        float q2 = qw[u * 9 + l2 * 3 + 2];
        rot_s[u][l2][0] = cosf(q0);        rot_s[u][l2][1] = sinf(q0);
        rot_s[u][l2][2] = cosf(0.5f * q1); rot_s[u][l2][3] = sinf(0.5f * q1);
        rot_s[u][l2][4] = cosf(q2);        rot_s[u][l2][5] = sinf(q2);
    }
    __syncthreads();   // one-time; GEMV loop below is barrier-free

    const int w    = t >> 6;        // wave id (0..3)
    const int l    = t & 63;        // lane
    const int jcol = l & 15;        // MFMA N-col == Wp row == proj output index
    const int kb   = (l >> 4) * 8;  // K offset within 32-wide K-step
    const int rb   = blockIdx.x * TB + w * 64;   // this wave's first row

    int rowA[4];
    #pragma unroll
    for (int g = 0; g < 4; ++g) {
        int r = rb + g * 16 + jcol;           // A-frag M-row for group g
        rowA[g] = (r < nrows) ? r : (nrows - 1);
    }

    const float bpj = bp[jcol];
    f32x4 acc[4];
    #pragma unroll
    for (int g = 0; g < 4; ++g) acc[g] = (f32x4){bpj, bpj, bpj, bpj};

    const float* wpb = Wp + jcol * 256 + kb;

    auto load_step = [&](int s, float4 (&A)[4][2], float4 (&Wv)[2]) {
        const float* wp_p = wpb + s * 32;
        Wv[0] = *(const float4*)(wp_p);
        Wv[1] = *(const float4*)(wp_p + 4);
        #pragma unroll
        for (int g = 0; g < 4; ++g) {
            const float* xp = x + (size_t)rowA[g] * 256 + s * 32 + kb;
            A[g][0] = *(const float4*)xp;
            A[g][1] = *(const float4*)(xp + 4);
        }
    };

    auto cvt = [&](const float4& p0, const float4& p1, Frag& hi, Frag& lo) {
        float f[8] = {p0.x, p0.y, p0.z, p0.w, p1.x, p1.y, p1.z, p1.w};
        #pragma unroll
        for (int e = 0; e < 8; ++e) {
            uint hb = f2bf_bits(f[e]);
            hi.u[e] = (ushort)hb;
            float r = f[e] - bf2f(hb);
            lo.u[e] = (ushort)f2bf_bits(r);
        }
    };

    auto process = [&](float4 (&A)[4][2], float4 (&Wv)[2]) {
        Frag bhi, blo;
        cvt(Wv[0], Wv[1], bhi, blo);
        #pragma unroll
        for (int g = 0; g < 4; ++g) {
            Frag ahi, alo;
            cvt(A[g][0], A[g][1], ahi, alo);
            acc[g] = __builtin_amdgcn_mfma_f32_16x16x32_bf16(ahi.v, bhi.v, acc[g], 0, 0, 0);
            acc[g] = __builtin_amdgcn_mfma_f32_16x16x32_bf16(alo.v, bhi.v, acc[g], 0, 0, 0);
            acc[g] = __builtin_amdgcn_mfma_f32_16x16x32_bf16(ahi.v, blo.v, acc[g], 0, 0, 0);
        }
    };

    // ---- register-double-buffered MFMA GEMV: 8 K-steps of 32 cols ----
    float4 A0[4][2], A1[4][2], W0[2], W1v[2];
    load_step(0, A0, W0);
    #pragma unroll
    for (int ss = 0; ss < 4; ++ss) {
        load_step(2 * ss + 1, A1, W1v);
        process(A0, W0);                       // A1/W1 stay in flight
        if (ss < 3) load_step(2 * ss + 2, A0, W0);
        process(A1, W1v);                      // A0-next stays in flight
    }

    // ---- intra-wave transpose via private LDS region (no barrier) ----
    #pragma unroll
    for (int g = 0; g < 4; ++g)
        #pragma unroll
        for (int r = 0; r < 4; ++r)
            proj_s[w][(g * 16 + (l >> 4) * 4 + r) * 20 + jcol] = acc[g][r];

    float pr[16];
    const float* myrow = &proj_s[w][l * 20];
    #pragma unroll
    for (int j4 = 0; j4 < 4; ++j4) {
        float4 v = *(const float4*)(myrow + j4 * 4);
        pr[j4 * 4 + 0] = v.x; pr[j4 * 4 + 1] = v.y;
        pr[j4 * 4 + 2] = v.z; pr[j4 * 4 + 3] = v.w;
    }

    // ---- 8 single-qubit circuits (R1-verified math) ----
    float q[8];
    #pragma unroll
    for (int u = 0; u < 8; ++u) {
        float th0 = fast_tanh(pr[2 * u + 0]);
        float th1 = fast_tanh(pr[2 * u + 1]);
        float c  = __cosf(0.5f * PI_F * th0);
        float s  = __sinf(0.5f * PI_F * th0);
        float zr = __cosf(PI_F * th1);
        float zi = __sinf(PI_F * th1);

        float ar = c, ai = 0.0f, br = s, bi = 0.0f;
        #pragma unroll
        for (int l2 = 0; l2 < 3; ++l2) {
            if (l2 > 0) {
                float nar = c * ar - s * br, nai = c * ai - s * bi;
                float nbr = s * ar + c * br, nbi = s * ai + c * bi;
                ar = nar; ai = nai; br = nbr; bi = nbi;
            }
            float e0r = rot_s[u][l2][0], e0i = rot_s[u][l2][1];
            float p2r = zr * e0r - zi * e0i;
            float p2q = zr * e0i + zi * e0r;
            float nbr = br * p2r - bi * p2q, nbi = br * p2q + bi * p2r;
            br = nbr; bi = nbi;
            float c1 = rot_s[u][l2][2], s1 = rot_s[u][l2][3];
            float tar = c1 * ar - s1 * br, tai = c1 * ai - s1 * bi;
            float tbr = s1 * ar + c1 * br, tbi = s1 * ai + c1 * bi;
            ar = tar; ai = tai; br = tbr; bi = tbi;
            if (l2 < 2) {
                float e2r = rot_s[u][l2][4], e2i = rot_s[u][l2][5];
                float ubr = br * e2r - bi * e2i, ubi = br * e2i + bi * e2r;
                br = ubr; bi = ubi;
            }
        }
        q[u] = (ar * ar + ai * ai) - (br * br + bi * bi);
    }

    // ---- head ----
    float ov[10];
    #pragma unroll
    for (int c2 = 0; c2 < 10; ++c2) ov[c2] = b2_s[c2];
    #pragma unroll
    for (int j = 0; j < 32; ++j) {
        float h = b1_s[j];
        #pragma unroll
        for (int u = 0; u < 8; ++u) h = fmaf(q[u], w1_s[j * 8 + u], h);
        h = fmaxf(h, 0.0f);
        #pragma unroll
        for (int c2 = 0; c2 < 10; ++c2) ov[c2] = fmaf(h, w2_s[c2 * 32 + j], ov[c2]);
    }

    const int row = rb + l;
    if (row < nrows) {
        float2* orow = (float2*)(out + (size_t)row * 10);
        orow[0] = make_float2(ov[0], ov[1]);
        orow[1] = make_float2(ov[2], ov[3]);
        orow[2] = make_float2(ov[4], ov[5]);
        orow[3] = make_float2(ov[6], ov[7]);
        orow[4] = make_float2(ov[8], ov[9]);
    }
}

extern "C" void kernel_launch(void* const* d_in, const int* in_sizes, int n_in,
                              void* d_out, int out_size, void* d_ws, size_t ws_size,
                              hipStream_t stream) {
    const float* x  = (const float*)d_in[0];
    const float* Wp = (const float*)d_in[1];
    const float* bp = (const float*)d_in[2];
    const float* qw = (const float*)d_in[3];
    const float* W1 = (const float*)d_in[4];
    const float* b1 = (const float*)d_in[5];
    const float* W2 = (const float*)d_in[6];
    const float* b2 = (const float*)d_in[7];
    float* out = (float*)d_out;

    const int nrows = in_sizes[0] / 256;
    const int nblocks = (nrows + TB - 1) / TB;
    sqru_fused_kernel<<<nblocks, TB, 0, stream>>>(x, Wp, bp, qw, W1, b1, W2, b2, out, nrows);
}

// Round 5
// 35.725 us; speedup vs baseline: 4.0271x; 1.0577x over previous
//
#include <hip/hip_runtime.h>
#include <math.h>

#define TB 256
#define PI_F 3.14159265358979323846f

typedef __attribute__((ext_vector_type(8))) short short8;
typedef __attribute__((ext_vector_type(4))) float f32x4;

union Frag { short8 v; ushort u[8]; };

__device__ __forceinline__ ushort f2bf(float f) {   // RNE fp32->bf16
    uint b = __float_as_uint(f);
    return (ushort)((b + 0x7fffu + ((b >> 16) & 1u)) >> 16);
}
__device__ __forceinline__ float bf2f(ushort h) { return __uint_as_float(((uint)h) << 16); }

__device__ __forceinline__ void cvt8(const float4& p0, const float4& p1, Frag& hi, Frag& lo) {
    float f[8] = {p0.x, p0.y, p0.z, p0.w, p1.x, p1.y, p1.z, p1.w};
    #pragma unroll
    for (int e = 0; e < 8; ++e) {
        ushort hb = f2bf(f[e]);
        hi.u[e] = hb;
        lo.u[e] = f2bf(f[e] - bf2f(hb));
    }
}

__device__ __forceinline__ float fast_tanh(float p) {
    float t = __expf(2.0f * p);
    return 1.0f - __fdividef(2.0f, t + 1.0f);
}

__global__ __launch_bounds__(TB, 4) void sqru_fused_kernel(
    const float* __restrict__ x, const float* __restrict__ Wp,
    const float* __restrict__ bp, const float* __restrict__ qw,
    const float* __restrict__ W1, const float* __restrict__ b1,
    const float* __restrict__ W2, const float* __restrict__ b2,
    float* __restrict__ out, int nrows)
{
    __shared__ ushort whi[512 * 8];        // 8 KB: Wp hi frags, [(s*4+kbi)*16+jc][8]
    __shared__ ushort wlo[512 * 8];        // 8 KB: Wp lo frags
    __shared__ float  proj_s[4][16 * 17];  // per-wave transpose, stride 17
    __shared__ float  qbuf[4][16][8];      // per-wave q gather
    __shared__ float  w1_s[32 * 8];
    __shared__ float  w2_s[10 * 32];
    __shared__ float  b1_s[32];
    __shared__ float  b2_s[10];
    __shared__ float  rot_s[8][3][6];

    const int t = threadIdx.x;

    // ---- one-time staging: W1/W2/biases/rot + Wp -> bf16 hi/lo MFMA frags ----
    if (t < 64) ((float4*)w1_s)[t] = ((const float4*)W1)[t];
    if (t < 80) ((float4*)w2_s)[t] = ((const float4*)W2)[t];
    if (t < 32) b1_s[t] = b1[t];
    if (t < 10) b2_s[t] = b2[t];
    if (t < 24) {
        int u = t / 3, l2 = t % 3;
        float q0 = qw[u * 9 + l2 * 3 + 0];
        float q1 = qw[u * 9 + l2 * 3 + 1];
        float q2 = qw[u * 9 + l2 * 3 + 2];
        rot_s[u][l2][0] = cosf(q0);        rot_s[u][l2][1] = sinf(q0);
        rot_s[u][l2][2] = cosf(0.5f * q1); rot_s[u][l2][3] = sinf(0.5f * q1);
        rot_s[u][l2][4] = cosf(q2);        rot_s[u][l2][5] = sinf(q2);
    }
    #pragma unroll
    for (int ff = 0; ff < 2; ++ff) {       // 512 frags, 2 per thread
        int f = t + ff * 256;
        int jc2 = f & 15, kb2 = (f >> 4) & 3, s2 = f >> 6;
        const float* wp = Wp + jc2 * 256 + s2 * 32 + kb2 * 8;
        float4 p0 = *(const float4*)wp;
        float4 p1 = *(const float4*)(wp + 4);
        Frag h, lo2;
        cvt8(p0, p1, h, lo2);
        ((short8*)whi)[f] = h.v;
        ((short8*)wlo)[f] = lo2.v;
    }
    __syncthreads();   // only barrier in the kernel

    const int w   = t >> 6;          // wave 0..3
    const int l   = t & 63;          // lane
    const int jc  = l & 15;          // M-row within tile AND B-col (proj index)
    const int kbi = l >> 4;          // K sub-offset group
    const int rb  = blockIdx.x * 64 + w * 16;   // wave's first row

    int row = rb + jc;
    if (row >= nrows) row = nrows - 1;
    const float* xp = x + (size_t)row * 256 + kbi * 8;

    const float bpj = bp[jc];
    f32x4 accm = {bpj, bpj, bpj, bpj};
    f32x4 accc = {0.0f, 0.0f, 0.0f, 0.0f};

    const short8* whi_f = (const short8*)whi;
    const short8* wlo_f = (const short8*)wlo;

    // ---- MFMA GEMV: 8 K-steps x 32 cols, 2-deep register prefetch ----
    float4 xA0 = *(const float4*)(xp + 0);
    float4 xB0 = *(const float4*)(xp + 4);
    float4 xA1 = *(const float4*)(xp + 32);
    float4 xB1 = *(const float4*)(xp + 36);

    #pragma unroll
    for (int ss = 0; ss < 4; ++ss) {
        {
            const int s = 2 * ss;
            Frag bh, bl, ah, al;
            bh.v = whi_f[(s * 4 + kbi) * 16 + jc];
            bl.v = wlo_f[(s * 4 + kbi) * 16 + jc];
            cvt8(xA0, xB0, ah, al);
            if (s + 2 < 8) {
                xA0 = *(const float4*)(xp + (s + 2) * 32);
                xB0 = *(const float4*)(xp + (s + 2) * 32 + 4);
            }
            accm = __builtin_amdgcn_mfma_f32_16x16x32_bf16(ah.v, bh.v, accm, 0, 0, 0);
            accc = __builtin_amdgcn_mfma_f32_16x16x32_bf16(al.v, bh.v, accc, 0, 0, 0);
            accc = __builtin_amdgcn_mfma_f32_16x16x32_bf16(ah.v, bl.v, accc, 0, 0, 0);
        }
        {
            const int s = 2 * ss + 1;
            Frag bh, bl, ah, al;
            bh.v = whi_f[(s * 4 + kbi) * 16 + jc];
            bl.v = wlo_f[(s * 4 + kbi) * 16 + jc];
            cvt8(xA1, xB1, ah, al);
            if (s + 2 < 8) {
                xA1 = *(const float4*)(xp + (s + 2) * 32);
                xB1 = *(const float4*)(xp + (s + 2) * 32 + 4);
            }
            accm = __builtin_amdgcn_mfma_f32_16x16x32_bf16(ah.v, bh.v, accm, 0, 0, 0);
            accc = __builtin_amdgcn_mfma_f32_16x16x32_bf16(al.v, bh.v, accc, 0, 0, 0);
            accc = __builtin_amdgcn_mfma_f32_16x16x32_bf16(ah.v, bl.v, accc, 0, 0, 0);
        }
    }

    // ---- intra-wave transpose: C[row=kbi*4+r][col=jc] -> proj_s (stride 17) ----
    #pragma unroll
    for (int r = 0; r < 4; ++r)
        proj_s[w][(kbi * 4 + r) * 17 + jc] = accm[r] + accc[r];

    // ---- unit-split circuit: 4 lanes per row, each does 2 of 8 units ----
    const int srow = l >> 2;
    const int s4   = l & 3;
    float4 pv = *(const float4*)&proj_s[w][srow * 17 + s4 * 4];

    float qv[2];
    #pragma unroll
    for (int uu = 0; uu < 2; ++uu) {
        const int u = 2 * s4 + uu;
        float p0 = (uu == 0) ? pv.x : pv.z;
        float p1 = (uu == 0) ? pv.y : pv.w;
        float th0 = fast_tanh(p0);
        float th1 = fast_tanh(p1);
        float c  = __cosf(0.5f * PI_F * th0);
        float s  = __sinf(0.5f * PI_F * th0);
        float zr = __cosf(PI_F * th1);
        float zi = __sinf(PI_F * th1);

        float ar = c, ai = 0.0f, br = s, bi = 0.0f;
        #pragma unroll
        for (int l2 = 0; l2 < 3; ++l2) {
            if (l2 > 0) {
                float nar = c * ar - s * br, nai = c * ai - s * bi;
                float nbr = s * ar + c * br, nbi = s * ai + c * bi;
                ar = nar; ai = nai; br = nbr; bi = nbi;
            }
            float e0r = rot_s[u][l2][0], e0i = rot_s[u][l2][1];
            float p2r = zr * e0r - zi * e0i;
            float p2q = zr * e0i + zi * e0r;
            float nbr = br * p2r - bi * p2q, nbi = br * p2q + bi * p2r;
            br = nbr; bi = nbi;
            float c1 = rot_s[u][l2][2], s1 = rot_s[u][l2][3];
            float tar = c1 * ar - s1 * br, tai = c1 * ai - s1 * bi;
            float tbr = s1 * ar + c1 * br, tbi = s1 * ai + c1 * bi;
            ar = tar; ai = tai; br = tbr; bi = tbi;
            if (l2 < 2) {
                float e2r = rot_s[u][l2][4], e2i = rot_s[u][l2][5];
                float ubr = br * e2r - bi * e2i, ubi = br * e2i + bi * e2r;
                br = ubr; bi = ubi;
            }
        }
        qv[uu] = (ar * ar + ai * ai) - (br * br + bi * bi);
    }

    // gather all 8 q's of my row via per-wave LDS
    *(float2*)&qbuf[w][srow][2 * s4] = make_float2(qv[0], qv[1]);
    float4 qa = *(const float4*)&qbuf[w][srow][0];
    float4 qb = *(const float4*)&qbuf[w][srow][4];

    // ---- head: each lane covers j = s4*8 .. s4*8+7, then 4-lane reduce ----
    float ov[10];
    #pragma unroll
    for (int c2 = 0; c2 < 10; ++c2) ov[c2] = 0.0f;
    #pragma unroll
    for (int jj = 0; jj < 8; ++jj) {
        const int j = s4 * 8 + jj;
        float h = b1_s[j];
        h = fmaf(qa.x, w1_s[j * 8 + 0], h);
        h = fmaf(qa.y, w1_s[j * 8 + 1], h);
        h = fmaf(qa.z, w1_s[j * 8 + 2], h);
        h = fmaf(qa.w, w1_s[j * 8 + 3], h);
        h = fmaf(qb.x, w1_s[j * 8 + 4], h);
        h = fmaf(qb.y, w1_s[j * 8 + 5], h);
        h = fmaf(qb.z, w1_s[j * 8 + 6], h);
        h = fmaf(qb.w, w1_s[j * 8 + 7], h);
        h = fmaxf(h, 0.0f);
        #pragma unroll
        for (int c2 = 0; c2 < 10; ++c2) ov[c2] = fmaf(h, w2_s[c2 * 32 + j], ov[c2]);
    }
    #pragma unroll
    for (int c2 = 0; c2 < 10; ++c2) {
        ov[c2] += __shfl_xor(ov[c2], 1);
        ov[c2] += __shfl_xor(ov[c2], 2);
        ov[c2] += b2_s[c2];
    }

    // ---- write: lane s4 stores float2 chunk s4; lane 0 also chunk 4 (static idx) ----
    const int orow = rb + srow;
    if (orow < nrows) {
        float2* op = (float2*)(out + (size_t)orow * 10);
        float lo = (s4 == 0) ? ov[0] : (s4 == 1) ? ov[2] : (s4 == 2) ? ov[4] : ov[6];
        float hi = (s4 == 0) ? ov[1] : (s4 == 1) ? ov[3] : (s4 == 2) ? ov[5] : ov[7];
        op[s4] = make_float2(lo, hi);
        if (s4 == 0) op[4] = make_float2(ov[8], ov[9]);
    }
}

extern "C" void kernel_launch(void* const* d_in, const int* in_sizes, int n_in,
                              void* d_out, int out_size, void* d_ws, size_t ws_size,
                              hipStream_t stream) {
    const float* x  = (const float*)d_in[0];
    const float* Wp = (const float*)d_in[1];
    const float* bp = (const float*)d_in[2];
    const float* qw = (const float*)d_in[3];
    const float* W1 = (const float*)d_in[4];
    const float* b1 = (const float*)d_in[5];
    const float* W2 = (const float*)d_in[6];
    const float* b2 = (const float*)d_in[7];
    float* out = (float*)d_out;

    const int nrows = in_sizes[0] / 256;
    const int nblocks = (nrows + 63) / 64;
    sqru_fused_kernel<<<nblocks, TB, 0, stream>>>(x, Wp, bp, qw, W1, b1, W2, b2, out, nrows);
}